// Round 6
// baseline (40.180 us; speedup 1.0000x reference)
//
#include <hip/hip_runtime.h>
#include <stdint.h>

#define NBATCH 4
#define NS 2048
#define ND 1024
#define NK 64
#define QSCALE 0.18033688011112042f  // 0.125 * log2(e), folded into Q

typedef __attribute__((ext_vector_type(4))) float f32x4;
typedef __attribute__((ext_vector_type(16))) float f32x16;
typedef __attribute__((ext_vector_type(8))) short bf16x8;
typedef unsigned short u16;
typedef unsigned int u32;
typedef unsigned long long u64;

__device__ __forceinline__ u16 f2bf(float f) {
  union { float f; u32 u; } v; v.f = f;
  u32 u = v.u;
  u += 0x7FFFu + ((u >> 16) & 1u);   // RNE
  return (u16)(u >> 16);
}

__device__ __forceinline__ u32 pk2(float lo, float hi) {
  u32 r;
  asm("v_cvt_pk_bf16_f32 %0, %1, %2" : "=v"(r) : "v"(lo), "v"(hi));
  return r;
}

// ---------------------------------------------------------------------------
// Kernel 0: W ([1024][64] f32, x3) -> Wt [192][1024] bf16 (transposed).
// ---------------------------------------------------------------------------
__global__ __launch_bounds__(256) void wtrans_kernel(
    const float* __restrict__ Wq, const float* __restrict__ Wk,
    const float* __restrict__ Wv, u16* __restrict__ Wt) {
  __shared__ float tile[64][65];
  int blk = blockIdx.x;            // 48 blocks: 3 matrices x 16 d-tiles
  int m = blk >> 4, dt = blk & 15;
  const float* W = (m == 0) ? Wq : (m == 1) ? Wk : Wv;
  int d0 = dt * 64;
  int t = threadIdx.x;
#pragma unroll
  for (int i = 0; i < 16; i++) {
    int idx = t + 256 * i;
    int dd = idx >> 6, c = idx & 63;
    tile[dd][c] = W[(d0 + dd) * 64 + c];
  }
  __syncthreads();
#pragma unroll
  for (int i = 0; i < 16; i++) {
    int idx = t + 256 * i;
    int c = idx >> 6, dd = idx & 63;
    Wt[(m * 64 + c) * 1024 + d0 + dd] = f2bf(tile[dd][c]);
  }
}

// ---------------------------------------------------------------------------
// Kernel 1: QKV projection, LDS-staged (unchanged from R5 — verified).
// ---------------------------------------------------------------------------
__global__ __launch_bounds__(512) void qkv_kernel(
    const float* __restrict__ x, const u16* __restrict__ Wt,
    const float* __restrict__ Bq, const float* __restrict__ Bk,
    const float* __restrict__ Bv, u16* __restrict__ Qf,
    u16* __restrict__ Kf, u16* __restrict__ Vf) {
  __shared__ __attribute__((aligned(16))) char lds[57344];
  char* ldsx = lds;              // [2][4096]  x-tile  (32 rows x 64 k bf16)
  char* ldsw = lds + 8192;       // [2][24576] Wt-tile (192 cols x 64 k bf16)

  int tid = threadIdx.x;
  int w = tid >> 6, lane = tid & 63;
  int g = lane >> 4, c = lane & 15;
  int rh = w & 1, cq = w >> 1;

  int xrow = tid >> 4;                    // 0..31
  int xp4  = tid & 15;                    // 16B piece within 256B f32 row
  const float* xsrc = x + ((long)blockIdx.x * 32 + xrow) * ND + xp4 * 4;
  int xwoff = xrow * 128 + ((xp4 * 8) ^ ((xrow & 7) << 4));

  int wrow = tid >> 3;                    // 0..63 within each 64-col group
  int wslot = tid & 7;                    // 16B piece within 128B bf16 row
  const u16* wsrc0 = Wt + (long)wrow * ND + wslot * 8;
  const u16* wsrc1 = Wt + (long)(64 + wrow) * ND + wslot * 8;
  const u16* wsrc2 = Wt + (long)(128 + wrow) * ND + wslot * 8;
  int wswz = (wrow & 7) << 4;
  int wwoff0 = wrow * 128 + ((wslot * 16) ^ wswz);
  int wwoff1 = (64 + wrow) * 128 + ((wslot * 16) ^ wswz);
  int wwoff2 = (128 + wrow) * 128 + ((wslot * 16) ^ wswz);

  int rowa = rh * 16 + c;
  int aswz = (rowa & 7) << 4;
  int aoff0 = rowa * 128 + ((g * 16) ^ aswz);
  int aoff1 = rowa * 128 + ((64 + g * 16) ^ aswz);
  int boff00, boff01, boff10, boff11, boff20, boff21;
  {
    int col = cq * 48 + c;
    int bz = (col & 7) << 4;
    boff00 = col * 128 + ((g * 16) ^ bz);
    boff01 = col * 128 + ((64 + g * 16) ^ bz);
    col += 16; bz = (col & 7) << 4;
    boff10 = col * 128 + ((g * 16) ^ bz);
    boff11 = col * 128 + ((64 + g * 16) ^ bz);
    col += 16; bz = (col & 7) << 4;
    boff20 = col * 128 + ((g * 16) ^ bz);
    boff21 = col * 128 + ((64 + g * 16) ^ bz);
  }

  f32x4 acc[3];
#pragma unroll
  for (int tt = 0; tt < 3; tt++) acc[tt] = (f32x4){0.f, 0.f, 0.f, 0.f};

  f32x4 xst;
  bf16x8 wst0, wst1, wst2;

#define LOADS(T) do {                                   \
    xst  = *(const f32x4*)(xsrc + (T) * 64);            \
    wst0 = *(const bf16x8*)(wsrc0 + (T) * 64);          \
    wst1 = *(const bf16x8*)(wsrc1 + (T) * 64);          \
    wst2 = *(const bf16x8*)(wsrc2 + (T) * 64);          \
  } while (0)

#define WRITES(NB) do {                                 \
    u32 lo_ = pk2(xst[0], xst[1]);                      \
    u32 hi_ = pk2(xst[2], xst[3]);                      \
    *(u64*)(ldsx + (NB) * 4096 + xwoff) = ((u64)hi_ << 32) | lo_; \
    *(bf16x8*)(ldsw + (NB) * 24576 + wwoff0) = wst0;    \
    *(bf16x8*)(ldsw + (NB) * 24576 + wwoff1) = wst1;    \
    *(bf16x8*)(ldsw + (NB) * 24576 + wwoff2) = wst2;    \
  } while (0)

#define COMPUTE(B) do {                                 \
    const char* xb_ = ldsx + (B) * 4096;                \
    const char* wb_ = ldsw + (B) * 24576;               \
    bf16x8 a0_ = *(const bf16x8*)(xb_ + aoff0);         \
    bf16x8 a1_ = *(const bf16x8*)(xb_ + aoff1);         \
    acc[0] = __builtin_amdgcn_mfma_f32_16x16x32_bf16(a0_, *(const bf16x8*)(wb_ + boff00), acc[0], 0, 0, 0); \
    acc[0] = __builtin_amdgcn_mfma_f32_16x16x32_bf16(a1_, *(const bf16x8*)(wb_ + boff01), acc[0], 0, 0, 0); \
    acc[1] = __builtin_amdgcn_mfma_f32_16x16x32_bf16(a0_, *(const bf16x8*)(wb_ + boff10), acc[1], 0, 0, 0); \
    acc[1] = __builtin_amdgcn_mfma_f32_16x16x32_bf16(a1_, *(const bf16x8*)(wb_ + boff11), acc[1], 0, 0, 0); \
    acc[2] = __builtin_amdgcn_mfma_f32_16x16x32_bf16(a0_, *(const bf16x8*)(wb_ + boff20), acc[2], 0, 0, 0); \
    acc[2] = __builtin_amdgcn_mfma_f32_16x16x32_bf16(a1_, *(const bf16x8*)(wb_ + boff21), acc[2], 0, 0, 0); \
  } while (0)

  LOADS(0);
  WRITES(0);
  __syncthreads();
#pragma unroll
  for (int t = 0; t < 16; t++) {
    if (t < 15) LOADS(t + 1);
    __builtin_amdgcn_sched_barrier(0);
    COMPUTE(t & 1);
    if (t < 15) WRITES((t + 1) & 1);
    __syncthreads();
  }
#undef LOADS
#undef WRITES
#undef COMPUTE

  // epilogue: bias + write in MFMA-fragment order
  long r0 = (long)blockIdx.x * 32 + rh * 16 + 4 * g;
#pragma unroll
  for (int tt = 0; tt < 3; tt++) {
    int colg = cq * 48 + tt * 16 + c;
    int mtx = colg >> 6;                 // 0=Q 1=K 2=V (wave-uniform)
    int col = colg & 63;
    const float* Bias = (mtx == 0) ? Bq : (mtx == 1) ? Bk : Bv;
    u16* Out = (mtx == 0) ? Qf : (mtx == 1) ? Kf : Vf;
#pragma unroll
    for (int j = 0; j < 4; j++) {
      long r = r0 + j;
      int srow = (int)(r & (NS - 1));
      int bb = (int)(r >> 11);
      float v = acc[tt][j] + Bias[srow * NK + col];
      if (mtx == 0) v *= QSCALE;
      long addr;
      if (mtx < 2) {
        addr = (((long)bb * 64 + (srow >> 5)) * 4 + (col >> 4)) * 512
             + (long)((srow & 31) + ((col >> 3) & 1) * 32) * 8 + (col & 7);
      } else {
        addr = ((((long)bb * 2 + ((col >> 5) & 1)) * 32 + (srow >> 6)) * 4 + ((srow >> 4) & 3)) * 512
             + (long)((col & 31) + ((srow >> 3) & 1) * 32) * 8 + (srow & 7);
      }
      Out[addr] = f2bf(v);
    }
  }
}

// ---------------------------------------------------------------------------
// Kernel 2: flash attention, LDS-staged KV shared by 4 waves.
// 256 blocks = (b, qt4 0..15, sp 0..3); block = 128 q-rows (4 waves x 32) x
// 512 KV rows (split sp), 8 steps of 64. KV fragments staged linearly into
// LDS once per step (waves 0-1 stage K, 2-3 stage V; 1KB/instr contiguous),
// each wave MFMAs the shared tile against its own Q. Cuts KV L2 traffic
// 256MB -> 16MB vs R5 (q-rows/block 32 -> 128). Per-wave math identical to
// R4/R5 (verified): swapped QK^T, no-max exp2 softmax, in-register P pack.
// Partials (unnormalized O, l) combined by combine_kernel.
// ---------------------------------------------------------------------------
__device__ __forceinline__ bf16x8 pack8(float p0, float p1, float p2, float p3,
                                        float p4, float p5, float p6, float p7,
                                        int hi) {
  u32 A = pk2(p0, p1), B = pk2(p2, p3), C = pk2(p4, p5), D = pk2(p6, p7);
  u32 sA = (u32)__shfl_xor((int)A, 32);
  u32 sB = (u32)__shfl_xor((int)B, 32);
  u32 sC = (u32)__shfl_xor((int)C, 32);
  u32 sD = (u32)__shfl_xor((int)D, 32);
  union { u32 w[4]; bf16x8 v; } u;
  u.w[0] = hi ? sC : A;
  u.w[1] = hi ? sD : B;
  u.w[2] = hi ? C : sA;
  u.w[3] = hi ? D : sB;
  return u.v;
}

__global__ __launch_bounds__(256) void attn_kernel(
    const u16* __restrict__ Qf, const u16* __restrict__ Kf,
    const u16* __restrict__ Vf, float* __restrict__ Opart,
    float* __restrict__ lpart) {
  __shared__ __attribute__((aligned(16))) char kv[2][16384];
  int tid = threadIdx.x;
  int w = tid >> 6, lane = tid & 63;
  int q = lane & 31, hi = lane >> 5;
  // bid -> (b, qt4, sp): XCD x owns 2 (b,sp) combos; 16 qt4 blocks per combo
  int bid = blockIdx.x;
  int xcd = bid & 7, i5 = bid >> 3;
  int combo = xcd * 2 + (i5 & 1);
  int qt4 = i5 >> 1;                       // 0..15
  int b = combo >> 2, sp = combo & 3;

  // Q fragments: wave-private 32 q-rows (chunk = b*64 + qt4*4 + w)
  bf16x8 qf[4];
  {
    const u16* qp = Qf + ((long)b * 64 + qt4 * 4 + w) * 2048 + lane * 8;
#pragma unroll
    for (int kk = 0; kk < 4; kk++) qf[kk] = *(const bf16x8*)(qp + kk * 512);
  }

  // staging: wave-uniform source roles (w0,w1: K halves; w2: V0; w3: V1)
  const char* ksrc = (const char*)(Kf + ((long)b * 64 + sp * 16) * 2048);
  const char* v0src = (const char*)(Vf + ((long)(b * 2) * 32 + sp * 8) * 2048);
  const char* v1src = (const char*)(Vf + ((long)(b * 2 + 1) * 32 + sp * 8) * 2048);
  const char* src_base = (w == 0) ? ksrc : (w == 1) ? (ksrc + 4096)
                       : (w == 2) ? v0src : v1src;
  long src_step = (w < 2) ? 8192 : 4096;   // bytes per 64-kv step
  int ldsoff = w * 4096 + lane * 16;

  f32x16 o0, o1;
#pragma unroll
  for (int r = 0; r < 16; r++) { o0[r] = 0.f; o1[r] = 0.f; }
  float lacc[4] = {0.f, 0.f, 0.f, 0.f};

  bf16x8 g0, g1, g2, g3;
#define SLOAD(T) do {                                                   \
    const char* s_ = src_base + (long)(T) * src_step + lane * 16;       \
    g0 = *(const bf16x8*)(s_);                                          \
    g1 = *(const bf16x8*)(s_ + 1024);                                   \
    g2 = *(const bf16x8*)(s_ + 2048);                                   \
    g3 = *(const bf16x8*)(s_ + 3072);                                   \
  } while (0)
#define SWRITE(NB) do {                                                 \
    char* d_ = kv[NB] + ldsoff;                                         \
    *(bf16x8*)(d_)        = g0;                                         \
    *(bf16x8*)(d_ + 1024) = g1;                                         \
    *(bf16x8*)(d_ + 2048) = g2;                                         \
    *(bf16x8*)(d_ + 3072) = g3;                                         \
  } while (0)

#define ASTEP(T) do {                                                         \
    const char* base_ = kv[(T) & 1];                                          \
    bf16x8 kf0[4], kf1[4], vf0[4], vf1[4];                                    \
    _Pragma("unroll") for (int i = 0; i < 4; i++) {                           \
      kf0[i] = *(const bf16x8*)(base_ + i * 1024 + lane * 16);                \
      kf1[i] = *(const bf16x8*)(base_ + 4096 + i * 1024 + lane * 16);         \
      vf0[i] = *(const bf16x8*)(base_ + 8192 + i * 1024 + lane * 16);         \
      vf1[i] = *(const bf16x8*)(base_ + 12288 + i * 1024 + lane * 16);        \
    }                                                                         \
    f32x16 s0, s1;                                                            \
    _Pragma("unroll") for (int r = 0; r < 16; r++) { s0[r] = 0.f; s1[r] = 0.f; } \
    _Pragma("unroll") for (int i = 0; i < 4; i++)                             \
      s0 = __builtin_amdgcn_mfma_f32_32x32x16_bf16(kf0[i], qf[i], s0, 0, 0, 0); \
    _Pragma("unroll") for (int i = 0; i < 4; i++)                             \
      s1 = __builtin_amdgcn_mfma_f32_32x32x16_bf16(kf1[i], qf[i], s1, 0, 0, 0); \
    _Pragma("unroll") for (int r = 0; r < 16; r++) {                          \
      s0[r] = exp2f(s0[r]); s1[r] = exp2f(s1[r]);                             \
      lacc[r & 3] += s0[r] + s1[r];                                           \
    }                                                                         \
    bf16x8 pa[4];                                                             \
    pa[0] = pack8(s0[0], s0[1], s0[2], s0[3], s0[4], s0[5], s0[6], s0[7], hi);   \
    pa[1] = pack8(s0[8], s0[9], s0[10], s0[11], s0[12], s0[13], s0[14], s0[15], hi); \
    pa[2] = pack8(s1[0], s1[1], s1[2], s1[3], s1[4], s1[5], s1[6], s1[7], hi);   \
    pa[3] = pack8(s1[8], s1[9], s1[10], s1[11], s1[12], s1[13], s1[14], s1[15], hi); \
    _Pragma("unroll") for (int i = 0; i < 4; i++) {                           \
      o0 = __builtin_amdgcn_mfma_f32_32x32x16_bf16(pa[i], vf0[i], o0, 0, 0, 0); \
      o1 = __builtin_amdgcn_mfma_f32_32x32x16_bf16(pa[i], vf1[i], o1, 0, 0, 0); \
    }                                                                         \
  } while (0)

  SLOAD(0);
  SWRITE(0);
  __syncthreads();
#pragma unroll
  for (int t = 0; t < 8; t++) {
    if (t < 7) SLOAD(t + 1);
    ASTEP(t);
    if (t < 7) SWRITE((t + 1) & 1);
    __syncthreads();
  }
#undef SLOAD
#undef SWRITE
#undef ASTEP

  float lt = (lacc[0] + lacc[1]) + (lacc[2] + lacc[3]);
  lt += __shfl_xor(lt, 32);

  // store partials (D row = (r&3)+8*(r>>2)+4*hi = q-row offset; col = k)
  long qbase = (long)b * NS + (qt4 * 4 + w) * 32;
  long ob = (long)sp * (NBATCH * NS * NK);
#pragma unroll
  for (int r = 0; r < 16; r++) {
    int qq = (r & 3) + 8 * (r >> 2) + 4 * hi;
    float* op = Opart + ob + (qbase + qq) * NK + q;
    op[0]  = o0[r];
    op[32] = o1[r];
  }
  if (hi == 0) lpart[sp * (NBATCH * NS) + qbase + q] = lt;
}

// ---------------------------------------------------------------------------
// Kernel 3: combine split-KV partials (sum of unnormalized O and l).
// ---------------------------------------------------------------------------
__global__ __launch_bounds__(256) void combine_kernel(
    const float* __restrict__ Opart, const float* __restrict__ lpart,
    float* __restrict__ out, int nsplit) {
  int gid = blockIdx.x * 256 + threadIdx.x;     // 131072 = 8192 rows * 16
  int rw = gid >> 4, c4 = (gid & 15) * 4;
  f32x4 a = (f32x4){0.f, 0.f, 0.f, 0.f};
  float l = 0.f;
  for (int sp = 0; sp < nsplit; sp++) {
    a += *(const f32x4*)(Opart + (long)sp * (NBATCH * NS * NK) + (long)rw * NK + c4);
    l += lpart[sp * (NBATCH * NS) + rw];
  }
  float inv = 1.0f / l;
  f32x4 r;
#pragma unroll
  for (int i = 0; i < 4; i++) r[i] = a[i] * inv;
  *(f32x4*)(out + (long)rw * NK + c4) = r;
}

// ---------------------------------------------------------------------------
extern "C" void kernel_launch(void* const* d_in, const int* in_sizes, int n_in,
                              void* d_out, int out_size, void* d_ws, size_t ws_size,
                              hipStream_t stream) {
  const float* x  = (const float*)d_in[0];
  const float* Wq = (const float*)d_in[1];
  const float* Bq = (const float*)d_in[2];
  const float* Wk = (const float*)d_in[3];
  const float* Bk = (const float*)d_in[4];
  const float* Wv = (const float*)d_in[5];
  const float* Bv = (const float*)d_in[6];
  float* out = (float*)d_out;

  char* ws = (char*)d_ws;
  u16* Wt = (u16*)ws;                         // 384 KB
  u16* Qf = (u16*)(ws + 393216);              // 1 MB, fragment order
  u16* Kf = (u16*)(ws + 1441792);             // 1 MB, fragment order
  u16* Vf = (u16*)(ws + 2490368);             // 1 MB, fragment order
  float* lpart = (float*)(ws + 3538944);      // 4 * 32 KB = 128 KB
  float* Opart = (float*)(ws + 3801088);      // 4 * 2 MB = 8 MB

  wtrans_kernel<<<dim3(48), dim3(256), 0, stream>>>(Wq, Wk, Wv, Wt);
  qkv_kernel<<<dim3(256), dim3(512), 0, stream>>>(x, Wt, Bq, Bk, Bv, Qf, Kf, Vf);
  attn_kernel<<<dim3(256), dim3(256), 0, stream>>>(Qf, Kf, Vf, Opart, lpart);
  combine_kernel<<<dim3(512), dim3(256), 0, stream>>>(Opart, lpart, out, 4);
}